// Round 2
// baseline (1101.468 us; speedup 1.0000x reference)
//
#include <hip/hip_runtime.h>
#include <stdint.h>

// ---------------------------------------------------------------------------
// FixedPointLSTM (B=64, T=256, I=512, H=1024), fixed-point Q8.8 with hard
// activations. All fxp grid values are exactly representable in fp16; fp16
// MFMA with fp32 accumulate matches the numpy reference to ~1 grid step.
//
// R12 = R10 (verified 1070 us, lstm 869 us) + vmcnt-FIFO overlap fixes.
// R11 (sc0 intra-XCD comm) FAILED correctness -> all communication reverted
// to R10's agent-scope protocol verbatim. R12 changes only ISSUE PLACEMENT
// of non-protocol memory ops around wave 0's poll:
//  1) w0's out-stores: issued before barrier A (drain merges with the h-store
//     L3 ack) instead of after the flag, where their HBM ack was serialized
//     ahead of the next poll's s_waitcnt vmcnt(0) (FIFO drain).
//  2) w0's gx prefetch: issued after barrier B (drains at barrier C together
//     with the stage loads) instead of before the poll.
//  3) poll exits without waiting for the block's OWN flag ack (own h data is
//     already L3-visible at barrier A; remote readers still see the real
//     flag). Waves 1-3 keep R10 placement (their drains hide under the poll).
// Protocol structure (per-block flags, w0 poll, barrier-then-flag) unchanged;
// R8 (tag-in-band) and R9 (per-wave flags) regressed and stay out.
// ---------------------------------------------------------------------------

typedef _Float16 h8 __attribute__((ext_vector_type(8)));
typedef _Float16 h4 __attribute__((ext_vector_type(4)));
typedef float f4 __attribute__((ext_vector_type(4)));
typedef unsigned long long u64;

#define MFMA16(a, b, c) __builtin_amdgcn_mfma_f32_16x16x32_f16(a, b, c, 0, 0, 0)

__device__ __forceinline__ float fxp(float x) {
  float q = rintf(x * 256.0f) * 0.00390625f;
  return fminf(fmaxf(q, -128.0f), 127.99609375f);
}

// round-only: for values provably in [-128, 127.996] the clamp is a no-op.
__device__ __forceinline__ float fxp_rnd(float x) {
  return rintf(x * 256.0f) * 0.00390625f;
}

__device__ __forceinline__ float hsig(float x) {
  return fminf(fmaxf(x / 6.0f + 0.5f, 0.0f), 1.0f);  // IEEE div to match np
}

// ---- quantize fp32 -> fxp grid, store fp16 ---------------------------------
__global__ void qf16_kernel(const float* __restrict__ in,
                            _Float16* __restrict__ out, int n4) {
  int i = blockIdx.x * 256 + threadIdx.x;
  if (i < n4) {
    float4 v = ((const float4*)in)[i];
    h4 o;
    o[0] = (_Float16)fxp(v.x); o[1] = (_Float16)fxp(v.y);
    o[2] = (_Float16)fxp(v.z); o[3] = (_Float16)fxp(v.w);
    ((h4*)out)[i] = o;
  }
}

// quantize + transpose x: in [64][256][512] -> rows m = t*64+b, [16384][512]
__global__ void qx_kernel(const float* __restrict__ in,
                          _Float16* __restrict__ out) {
  int i4 = blockIdx.x * 256 + threadIdx.x;  // over 16384*128 float4s
  int col4 = i4 & 127;
  int row = i4 >> 7;  // b*256 + t
  int b = row >> 8, tt = row & 255;
  float4 v = ((const float4*)in)[i4];
  h4 o;
  o[0] = (_Float16)fxp(v.x); o[1] = (_Float16)fxp(v.y);
  o[2] = (_Float16)fxp(v.z); o[3] = (_Float16)fxp(v.w);
  ((h4*)out)[(size_t)((tt << 6) + b) * 128 + col4] = o;
}

__global__ void qf32_kernel(const float* __restrict__ in,
                            float* __restrict__ out, int n4) {
  int i = blockIdx.x * 256 + threadIdx.x;
  if (i < n4) {
    float4 v = ((const float4*)in)[i];
    float4 o;
    o.x = fxp(v.x); o.y = fxp(v.y); o.z = fxp(v.z); o.w = fxp(v.w);
    ((float4*)out)[i] = o;
  }
}

// h0 -> hbuf buffer 0, layout [grp=8][buf=2][row=8][1024] fp16
__global__ void qh0_kernel(const float* __restrict__ in,
                           _Float16* __restrict__ hbuf) {
  int i = blockIdx.x * 256 + threadIdx.x;  // over 64*1024/4
  int col4 = i & 255, b = i >> 8;
  float4 v = ((const float4*)in)[i];
  h4 o;
  o[0] = (_Float16)fxp(v.x); o[1] = (_Float16)fxp(v.y);
  o[2] = (_Float16)fxp(v.z); o[3] = (_Float16)fxp(v.w);
  *(h4*)(hbuf + (size_t)(b >> 3) * 16384 + (b & 7) * 1024 + col4 * 4) = o;
}

// ---- async global->LDS helper (width 16B; LDS dest = wave-uniform base) ----
__device__ __forceinline__ void gload_lds16(const _Float16* g, _Float16* l) {
  __builtin_amdgcn_global_load_lds(
      (const __attribute__((address_space(1))) uint32_t*)g,
      (__attribute__((address_space(3))) uint32_t*)l, 16, 0, 0);
}

// ---------------------------------------------------------------------------
// gx = fxp(x_q @ w_ih_q^T + b_ih_q), packed [T=256][oct=8][rank=32][slot=128][8]
// fp16 (128 MB). slot = (w<<5)|(qh<<4)|(gate&1)<<3|(j&7); per-entry 8 fp16 =
// [tile0 r=0..3 | tile1 r=0..3], tile = gate>>1, r = b&3, qh = (b>>2)&1.
// ---------------------------------------------------------------------------
__global__ __launch_bounds__(256) void gemm_gx_kernel(
    const _Float16* __restrict__ Xq,   // [16384][512], m = t*64+b
    const _Float16* __restrict__ Wih,  // [4096][512]
    const float* __restrict__ bih,     // [4096]
    _Float16* __restrict__ gx)         // packed, see above
{
  __shared__ _Float16 As[128 * 32];
  __shared__ _Float16 Bs[128 * 32];
  const int tid = threadIdx.x;
  const int lane = tid & 63;
  const int w = tid >> 6;
  const int wm = (w >> 1) * 64;
  const int wn = (w & 1) * 64;
  const int m0 = blockIdx.x * 128;
  const int n0 = blockIdx.y * 128;
  const int cl = lane & 15, q = lane >> 4;

  f4 acc[4][4] = {};

  for (int k0 = 0; k0 < 512; k0 += 32) {
#pragma unroll
    for (int i = 0; i < 2; i++) {
      int idx = i * 256 + tid;
      int row = idx >> 2;
      int kc = (idx & 3) << 3;
      int wbase = (i * 256 + (tid & 192)) << 3;  // wave-uniform LDS base
      gload_lds16(Xq + (size_t)(m0 + row) * 512 + k0 + kc, As + wbase);
      gload_lds16(Wih + (size_t)(n0 + row) * 512 + k0 + kc, Bs + wbase);
    }
    __syncthreads();
    h8 af[4], bf[4];
#pragma unroll
    for (int mt = 0; mt < 4; mt++)
      af[mt] = *(const h8*)(As + (wm + mt * 16 + cl) * 32 + q * 8);
#pragma unroll
    for (int nt = 0; nt < 4; nt++)
      bf[nt] = *(const h8*)(Bs + (wn + nt * 16 + cl) * 32 + q * 8);
#pragma unroll
    for (int mt = 0; mt < 4; mt++)
#pragma unroll
      for (int nt = 0; nt < 4; nt++)
        acc[mt][nt] = MFMA16(af[mt], bf[nt], acc[mt][nt]);
    __syncthreads();
  }

  const int g = n0 >> 10;  // whole n-block lies in one gate
  const int tile = g >> 1, g1 = g & 1;
#pragma unroll
  for (int nt = 0; nt < 4; nt++) {
    const int n = n0 + wn + nt * 16 + cl;
    const float bv = bih[n];
    const int j = n & 1023;
    const int rank = j >> 5, wq = (j >> 3) & 3, c7 = j & 7;
#pragma unroll
    for (int mt = 0; mt < 4; mt++) {
      const int m = m0 + wm + mt * 16 + q * 4;  // 4-aligned
      const int b = m & 63, tt = m >> 6;
      const int oct = b >> 3, qh = (b >> 2) & 1;
      const int slot = (wq << 5) | (qh << 4) | (g1 << 3) | c7;
      h4 pk;
#pragma unroll
      for (int r = 0; r < 4; r++) pk[r] = (_Float16)fxp(acc[mt][nt][r] + bv);
      *(h4*)(gx + ((((size_t)tt * 8 + oct) * 32 + rank) * 128 + slot) * 8 +
             tile * 4) = pk;
    }
  }
}

// ---------------------------------------------------------------------------
// Persistent recurrence. 256 blocks x 256 threads, a255 pin -> 1 block/CU ->
// all blocks co-resident. Block = (grp = blockIdx&7, rank = blockIdx>>3);
// group owns batch rows 8g..8g+7; rank owns h-cols rank*32..+31 x 4 gates
// (128 W_hh rows in regs). Per step (R10 protocol + R12 issue placement):
//   [w1-3] gx prefetch (drains at B under poll) -> w0 polls 32 flags with no
//   prior outstanding VMEM -> barrier B -> [w0] gx prefetch -> stage 8x8B
//   coalesced agent loads -> ds_write_b64 (4-way banks) -> barrier C (drains
//   stage + gx + w0's out stores of t-1... none: w0 out pre-A) -> MFMA ->
//   gates -> h stores (2B agent atomics) -> [w0] out stores -> barrier A
//   (drains h + w0 out) -> tid0 flag -> [w1-3] out stores.
// ---------------------------------------------------------------------------
__global__ __launch_bounds__(256, 1) void lstm_kernel(
    const _Float16* __restrict__ Whh,  // [4096][1024] quantized
    const float* __restrict__ bhh,     // [4096] quantized
    const _Float16* __restrict__ gx,   // packed [256][8][32][128][8]
    const float* __restrict__ c0,      // [64][1024]
    _Float16* __restrict__ hbuf,       // [8][2][8][1024] fp16
    float* __restrict__ out,           // [64][256][1024] ++ h_n ++ c_n
    unsigned* __restrict__ flags)      // [8][32]
{
  // Residency pin: force total regs/wave > 256 -> 1 wave/SIMD -> 1 block/CU.
  asm volatile("v_accvgpr_write_b32 a255, 0" ::: "a255");

  const int tid = threadIdx.x;
  const int lane = tid & 63;
  const int w = tid >> 6;
  const int cl = lane & 15, q = lane >> 4;
  const int g01 = (lane >> 3) & 1;
  const int c7 = lane & 7;

  const int grp = blockIdx.x & 7;    // batch octet
  const int rank = blockIdx.x >> 3;  // 32-column slice owner

  const int jbase = (rank << 5) + (w << 3);         // block/wave col base
  const int row0 = (g01 << 10) + jbase + c7;        // gates i/f
  const int row1 = ((g01 + 2) << 10) + jbase + c7;  // gates g/o

  // persistent B fragments: 2 tiles x 32 k-steps x 4 regs = 256 regs
  h8 B0[32], B1[32];
#pragma unroll
  for (int kt = 0; kt < 32; kt++) {
    B0[kt] = *(const h8*)(Whh + (size_t)row0 * 1024 + (kt << 5) + (q << 3));
    B1[kt] = *(const h8*)(Whh + (size_t)row1 * 1024 + (kt << 5) + (q << 3));
  }
  const float bh0 = bhh[row0], bh1 = bhh[row1];
  const int jc = jbase + c7;        // h column 0..1023
  const int lrow = ((q & 1) << 2);  // local batch row base (valid q<2)
  const bool writer = ((lane & 8) == 0) && (q < 2);

  float c_st[4], h_last[4];
#pragma unroll
  for (int r = 0; r < 4; r++) {
    c_st[r] = c0[((grp << 3) + lrow + r) * 1024 + jc];
    h_last[r] = 0.0f;
  }

  // LDS h stage: 8 rows x 1032 halves (pad +8: fragment reads arow*1032 are
  // conflict-free, verified in R6). Staging: thread (row=tid>>5, c=tid&31)
  // loads u64s c+32j of its row (coalesced 256B/32 lanes), writes LDS at
  // row*1032 + 4c + 128j halves -> 4-way banks.
  __shared__ alignas(16) _Float16 hs[8 * 1032];
  const int arow = cl & 7;
  const u64* hb64 = (const u64*)hbuf;  // [grp: 4096][buf: 2048] u64s
  const size_t lsrc = (size_t)grp * 4096 + (size_t)((tid >> 5) << 8) + (tid & 31);
  _Float16* ldst = hs + (tid >> 5) * 1032 + ((tid & 31) << 2);

  unsigned* myflag = flags + (grp << 5) + rank;
  const u64* f2 = (const u64*)(flags + (grp << 5));  // 16 u64 per group
  const int myidx = rank >> 1;  // u64 slot containing our own flag

  for (int t = 0; t < 256; t++) {
    const size_t gxoff =
        ((((size_t)t * 8 + grp) * 32 + rank) * 128 + ((w << 5) | (lane & 31))) *
        8;
    h8 gv8;
    // w1-3: prefetch gx before the poll barrier; its drain (and that of the
    // out stores issued at the previous tail) lands at barrier B, hidden
    // under w0's poll. w0 must NOT have these outstanding during the poll:
    // the poll's s_waitcnt vmcnt(0) would serialize their HBM ack ahead of
    // every flag check (vmcnt is FIFO).
    if (w != 0 || t == 0) gv8 = *(const h8*)(gx + gxoff);

    if (t) {
      if (w == 0) {
        const unsigned tt = (unsigned)t;
        int it = 0;
        for (;;) {
          u64 v = __hip_atomic_load(&f2[lane & 15], __ATOMIC_RELAXED,
                                    __HIP_MEMORY_SCOPE_AGENT);
          unsigned lo = (unsigned)v, hi = (unsigned)(v >> 32);
          // own flag: our h data drained at barrier A before the flag store,
          // so our own slice is valid -- don't wait for our own flag's ack.
          if ((lane & 15) == myidx) {
            if (rank & 1) hi = tt; else lo = tt;
          }
          bool ok = (lo >= tt) && (hi >= tt);
          if (__ballot(ok) == ~0ull) break;
          if (++it > (1 << 14)) break;  // hang insurance (loudly wrong)
          __builtin_amdgcn_s_sleep(1);
        }
      }
      __syncthreads();  // B
      // w0's gx prefetch: issued post-B, drains at barrier C with the stage.
      if (w == 0) gv8 = *(const h8*)(gx + gxoff);
    }

    // ---- stage h_t (16KB): 8 coalesced 8B agent loads -> ds_write_b64 ----
    {
      const u64* src = hb64 + lsrc + (size_t)(t & 1) * 2048;
      u64 v0 = __hip_atomic_load(src + 0 * 32, __ATOMIC_RELAXED, __HIP_MEMORY_SCOPE_AGENT);
      u64 v1 = __hip_atomic_load(src + 1 * 32, __ATOMIC_RELAXED, __HIP_MEMORY_SCOPE_AGENT);
      u64 v2 = __hip_atomic_load(src + 2 * 32, __ATOMIC_RELAXED, __HIP_MEMORY_SCOPE_AGENT);
      u64 v3 = __hip_atomic_load(src + 3 * 32, __ATOMIC_RELAXED, __HIP_MEMORY_SCOPE_AGENT);
      u64 v4 = __hip_atomic_load(src + 4 * 32, __ATOMIC_RELAXED, __HIP_MEMORY_SCOPE_AGENT);
      u64 v5 = __hip_atomic_load(src + 5 * 32, __ATOMIC_RELAXED, __HIP_MEMORY_SCOPE_AGENT);
      u64 v6 = __hip_atomic_load(src + 6 * 32, __ATOMIC_RELAXED, __HIP_MEMORY_SCOPE_AGENT);
      u64 v7 = __hip_atomic_load(src + 7 * 32, __ATOMIC_RELAXED, __HIP_MEMORY_SCOPE_AGENT);
      *(u64*)(ldst + 0 * 128) = v0;
      *(u64*)(ldst + 1 * 128) = v1;
      *(u64*)(ldst + 2 * 128) = v2;
      *(u64*)(ldst + 3 * 128) = v3;
      *(u64*)(ldst + 4 * 128) = v4;
      *(u64*)(ldst + 5 * 128) = v5;
      *(u64*)(ldst + 6 * 128) = v6;
      *(u64*)(ldst + 7 * 128) = v7;
    }
    __syncthreads();  // C (drains stage loads + gx + w1-3 residual)

    f4 a0 = {}, a1 = {}, a2 = {}, a3 = {};
#pragma unroll
    for (int kt = 0; kt < 32; kt++) {
      h8 av = *(const h8*)(hs + arow * 1032 + (kt << 5) + (q << 3));
      if (kt & 1) { a1 = MFMA16(av, B0[kt], a1); a3 = MFMA16(av, B1[kt], a3); }
      else        { a0 = MFMA16(av, B0[kt], a0); a2 = MFMA16(av, B1[kt], a2); }
    }
    f4 g0 = a0 + a1;
    f4 g1 = a2 + a3;

    _Float16* hbw = hbuf + (size_t)grp * 16384 + ((t + 1) & 1) * 8192;
#pragma unroll
    for (int r = 0; r < 4; r++) {
      float gv0 = fxp((float)gv8[r] + fxp(g0[r] + bh0));      // i or f
      float gv1 = fxp((float)gv8[4 + r] + fxp(g1[r] + bh1));  // g or o
      float s0 = fxp_rnd(hsig(gv0));                        // in [0,1]
      float s1t = fxp_rnd(fminf(fmaxf(gv1, -1.0f), 1.0f));  // in [-1,1]
      float s1s = fxp_rnd(hsig(gv1));
      float s1 = (lane & 8) ? s1s : s1t;
      float p0 = __shfl_xor(s0, 8);
      float p1 = __shfl_xor(s1, 8);
      float iv = writer ? s0 : p0;
      float fv = writer ? p0 : s0;
      float gv = writer ? s1 : p1;
      float ov = writer ? p1 : s1;
      float cn = fxp(fv * c_st[r] + iv * gv);
      c_st[r] = cn;
      float hn = fxp_rnd(ov * fminf(fmaxf(cn, -1.0f), 1.0f));  // in [-1,1]
      h_last[r] = hn;
      if (writer) {
        unsigned short hbits = __builtin_bit_cast(unsigned short, (_Float16)hn);
        __hip_atomic_store((unsigned short*)&hbw[(lrow + r) * 1024 + jc], hbits,
                           __ATOMIC_RELAXED, __HIP_MEMORY_SCOPE_AGENT);
      }
    }
    // w0's out stores issue BEFORE barrier A: their HBM ack merges with the
    // h-store drain instead of stalling the next step's poll (vmcnt FIFO).
    if (w == 0 && writer) {
#pragma unroll
      for (int r = 0; r < 4; r++)
        __builtin_nontemporal_store(
            h_last[r],
            &out[((size_t)((grp << 3) + lrow + r) * 256 + t) * 1024 + jc]);
    }
    __syncthreads();  // A (drains h atomics + w0 out stores)
    if (tid == 0)
      __hip_atomic_store(myflag, (unsigned)(t + 1), __ATOMIC_RELAXED,
                         __HIP_MEMORY_SCOPE_AGENT);
    // w1-3 out stores after the flag: drain lands at next barrier B, hidden
    // under w0's poll.
    if (w != 0 && writer) {
#pragma unroll
      for (int r = 0; r < 4; r++)
        __builtin_nontemporal_store(
            h_last[r],
            &out[((size_t)((grp << 3) + lrow + r) * 256 + t) * 1024 + jc]);
    }
  }

  if (writer) {
#pragma unroll
    for (int r = 0; r < 4; r++) {
      out[16777216 + (size_t)((grp << 3) + lrow + r) * 1024 + jc] = h_last[r];
      out[16777216 + 65536 + (size_t)((grp << 3) + lrow + r) * 1024 + jc] =
          c_st[r];
    }
  }
}

// ---------------------------------------------------------------------------
extern "C" void kernel_launch(void* const* d_in, const int* in_sizes, int n_in,
                              void* d_out, int out_size, void* d_ws,
                              size_t ws_size, hipStream_t stream) {
  const float* x    = (const float*)d_in[0];
  const float* w_ih = (const float*)d_in[1];
  const float* w_hh = (const float*)d_in[2];
  const float* b_ih = (const float*)d_in[3];
  const float* b_hh = (const float*)d_in[4];
  const float* h0   = (const float*)d_in[5];
  const float* c0   = (const float*)d_in[6];
  float* out = (float*)d_out;

  // workspace layout (bytes); total ~156.3 MB
  char* ws = (char*)d_ws;
  unsigned* flags = (unsigned*)ws;                    // [8][32] u32 = 1 KB
  _Float16* hbuf  = (_Float16*)(ws + 2048);           // 8*2*8*1024*2 = 256 KB
  _Float16* whhq  = (_Float16*)(ws + 264192);         // 8 MB
  _Float16* wihq  = (_Float16*)(ws + 8652800);        // 4 MB
  float*    bihq  = (float*)(ws + 12847104);          // 16 KB
  float*    bhhq  = (float*)(ws + 12863488);          // 16 KB
  _Float16* xq    = (_Float16*)(ws + 12879872);       // 16 MB
  _Float16* gxb   = (_Float16*)(ws + 29657088);       // 128 MB packed

  hipMemsetAsync(flags, 0, 2048, stream);
  qf16_kernel<<<dim3(4096), 256, 0, stream>>>(w_hh, whhq, 4194304 / 4);
  qf16_kernel<<<dim3(2048), 256, 0, stream>>>(w_ih, wihq, 2097152 / 4);
  qx_kernel<<<dim3(8192), 256, 0, stream>>>(x, xq);
  qh0_kernel<<<dim3(64), 256, 0, stream>>>(h0, hbuf);
  qf32_kernel<<<dim3(4), 256, 0, stream>>>(b_ih, bihq, 4096 / 4);
  qf32_kernel<<<dim3(4), 256, 0, stream>>>(b_hh, bhhq, 4096 / 4);
  gemm_gx_kernel<<<dim3(128, 32), 256, 0, stream>>>(xq, wihq, bihq, gxb);
  lstm_kernel<<<dim3(256), 256, 0, stream>>>(whhq, bhhq, gxb, c0, hbuf, out,
                                             flags);
}

// Round 3
// 1063.365 us; speedup vs baseline: 1.0358x; 1.0358x over previous
//
#include <hip/hip_runtime.h>
#include <stdint.h>

// ---------------------------------------------------------------------------
// FixedPointLSTM (B=64, T=256, I=512, H=1024), fixed-point Q8.8 with hard
// activations. All fxp grid values are exactly representable in fp16; fp16
// MFMA with fp32 accumulate matches the numpy reference to ~1 grid step.
//
// R13 = R10 (verified 869 us lstm / 1070 us total) + coalesced h publication.
// History: R11 (sc0 intra-XCD comm) FAILED correctness; R12 (vmcnt-FIFO
// placement shuffle) regressed 869->899. Both reverted; protocol and issue
// placement below are R10 verbatim.
// R13's single change: h-store publication. R10 issued 64 scattered 2-byte
// agent atomic stores per wave (256/block, 65536/step device-wide) -- pure
// transaction-count cost on the L3 store path and on barrier A's drain.
// Now: writers deposit h into a 128B per-wave LDS tile (conflict-free
// ds_write_b16), wave-local lgkmcnt(0), lanes 0-15 transpose-read
// (ds_read_b64, conflict-free) and issue 16 contiguous 8B agent stores per
// wave (row-contiguous 16B runs). Same bytes, 4x fewer transactions, same
// ordering (stores drain at barrier A before the flag).
// ---------------------------------------------------------------------------

typedef _Float16 h8 __attribute__((ext_vector_type(8)));
typedef _Float16 h4 __attribute__((ext_vector_type(4)));
typedef float f4 __attribute__((ext_vector_type(4)));
typedef unsigned long long u64;

#define MFMA16(a, b, c) __builtin_amdgcn_mfma_f32_16x16x32_f16(a, b, c, 0, 0, 0)

__device__ __forceinline__ float fxp(float x) {
  float q = rintf(x * 256.0f) * 0.00390625f;
  return fminf(fmaxf(q, -128.0f), 127.99609375f);
}

// round-only: for values provably in [-128, 127.996] the clamp is a no-op.
__device__ __forceinline__ float fxp_rnd(float x) {
  return rintf(x * 256.0f) * 0.00390625f;
}

__device__ __forceinline__ float hsig(float x) {
  return fminf(fmaxf(x / 6.0f + 0.5f, 0.0f), 1.0f);  // IEEE div to match np
}

// ---- quantize fp32 -> fxp grid, store fp16 ---------------------------------
__global__ void qf16_kernel(const float* __restrict__ in,
                            _Float16* __restrict__ out, int n4) {
  int i = blockIdx.x * 256 + threadIdx.x;
  if (i < n4) {
    float4 v = ((const float4*)in)[i];
    h4 o;
    o[0] = (_Float16)fxp(v.x); o[1] = (_Float16)fxp(v.y);
    o[2] = (_Float16)fxp(v.z); o[3] = (_Float16)fxp(v.w);
    ((h4*)out)[i] = o;
  }
}

// quantize + transpose x: in [64][256][512] -> rows m = t*64+b, [16384][512]
__global__ void qx_kernel(const float* __restrict__ in,
                          _Float16* __restrict__ out) {
  int i4 = blockIdx.x * 256 + threadIdx.x;  // over 16384*128 float4s
  int col4 = i4 & 127;
  int row = i4 >> 7;  // b*256 + t
  int b = row >> 8, tt = row & 255;
  float4 v = ((const float4*)in)[i4];
  h4 o;
  o[0] = (_Float16)fxp(v.x); o[1] = (_Float16)fxp(v.y);
  o[2] = (_Float16)fxp(v.z); o[3] = (_Float16)fxp(v.w);
  ((h4*)out)[(size_t)((tt << 6) + b) * 128 + col4] = o;
}

__global__ void qf32_kernel(const float* __restrict__ in,
                            float* __restrict__ out, int n4) {
  int i = blockIdx.x * 256 + threadIdx.x;
  if (i < n4) {
    float4 v = ((const float4*)in)[i];
    float4 o;
    o.x = fxp(v.x); o.y = fxp(v.y); o.z = fxp(v.z); o.w = fxp(v.w);
    ((float4*)out)[i] = o;
  }
}

// h0 -> hbuf buffer 0, layout [grp=8][buf=2][row=8][1024] fp16
__global__ void qh0_kernel(const float* __restrict__ in,
                           _Float16* __restrict__ hbuf) {
  int i = blockIdx.x * 256 + threadIdx.x;  // over 64*1024/4
  int col4 = i & 255, b = i >> 8;
  float4 v = ((const float4*)in)[i];
  h4 o;
  o[0] = (_Float16)fxp(v.x); o[1] = (_Float16)fxp(v.y);
  o[2] = (_Float16)fxp(v.z); o[3] = (_Float16)fxp(v.w);
  *(h4*)(hbuf + (size_t)(b >> 3) * 16384 + (b & 7) * 1024 + col4 * 4) = o;
}

// ---- async global->LDS helper (width 16B; LDS dest = wave-uniform base) ----
__device__ __forceinline__ void gload_lds16(const _Float16* g, _Float16* l) {
  __builtin_amdgcn_global_load_lds(
      (const __attribute__((address_space(1))) uint32_t*)g,
      (__attribute__((address_space(3))) uint32_t*)l, 16, 0, 0);
}

// ---------------------------------------------------------------------------
// gx = fxp(x_q @ w_ih_q^T + b_ih_q), packed [T=256][oct=8][rank=32][slot=128][8]
// fp16 (128 MB). slot = (w<<5)|(qh<<4)|(gate&1)<<3|(j&7); per-entry 8 fp16 =
// [tile0 r=0..3 | tile1 r=0..3], tile = gate>>1, r = b&3, qh = (b>>2)&1.
// ---------------------------------------------------------------------------
__global__ __launch_bounds__(256) void gemm_gx_kernel(
    const _Float16* __restrict__ Xq,   // [16384][512], m = t*64+b
    const _Float16* __restrict__ Wih,  // [4096][512]
    const float* __restrict__ bih,     // [4096]
    _Float16* __restrict__ gx)         // packed, see above
{
  __shared__ _Float16 As[128 * 32];
  __shared__ _Float16 Bs[128 * 32];
  const int tid = threadIdx.x;
  const int lane = tid & 63;
  const int w = tid >> 6;
  const int wm = (w >> 1) * 64;
  const int wn = (w & 1) * 64;
  const int m0 = blockIdx.x * 128;
  const int n0 = blockIdx.y * 128;
  const int cl = lane & 15, q = lane >> 4;

  f4 acc[4][4] = {};

  for (int k0 = 0; k0 < 512; k0 += 32) {
#pragma unroll
    for (int i = 0; i < 2; i++) {
      int idx = i * 256 + tid;
      int row = idx >> 2;
      int kc = (idx & 3) << 3;
      int wbase = (i * 256 + (tid & 192)) << 3;  // wave-uniform LDS base
      gload_lds16(Xq + (size_t)(m0 + row) * 512 + k0 + kc, As + wbase);
      gload_lds16(Wih + (size_t)(n0 + row) * 512 + k0 + kc, Bs + wbase);
    }
    __syncthreads();
    h8 af[4], bf[4];
#pragma unroll
    for (int mt = 0; mt < 4; mt++)
      af[mt] = *(const h8*)(As + (wm + mt * 16 + cl) * 32 + q * 8);
#pragma unroll
    for (int nt = 0; nt < 4; nt++)
      bf[nt] = *(const h8*)(Bs + (wn + nt * 16 + cl) * 32 + q * 8);
#pragma unroll
    for (int mt = 0; mt < 4; mt++)
#pragma unroll
      for (int nt = 0; nt < 4; nt++)
        acc[mt][nt] = MFMA16(af[mt], bf[nt], acc[mt][nt]);
    __syncthreads();
  }

  const int g = n0 >> 10;  // whole n-block lies in one gate
  const int tile = g >> 1, g1 = g & 1;
#pragma unroll
  for (int nt = 0; nt < 4; nt++) {
    const int n = n0 + wn + nt * 16 + cl;
    const float bv = bih[n];
    const int j = n & 1023;
    const int rank = j >> 5, wq = (j >> 3) & 3, c7 = j & 7;
#pragma unroll
    for (int mt = 0; mt < 4; mt++) {
      const int m = m0 + wm + mt * 16 + q * 4;  // 4-aligned
      const int b = m & 63, tt = m >> 6;
      const int oct = b >> 3, qh = (b >> 2) & 1;
      const int slot = (wq << 5) | (qh << 4) | (g1 << 3) | c7;
      h4 pk;
#pragma unroll
      for (int r = 0; r < 4; r++) pk[r] = (_Float16)fxp(acc[mt][nt][r] + bv);
      *(h4*)(gx + ((((size_t)tt * 8 + oct) * 32 + rank) * 128 + slot) * 8 +
             tile * 4) = pk;
    }
  }
}

// ---------------------------------------------------------------------------
// Persistent recurrence. 256 blocks x 256 threads, a255 pin -> 1 block/CU ->
// all blocks co-resident. Block = (grp = blockIdx&7, rank = blockIdx>>3);
// group owns batch rows 8g..8g+7; rank owns h-cols rank*32..+31 x 4 gates
// (128 W_hh rows in regs). Per step (R10 protocol):
//   gx prefetch -> w0 polls 32 per-block flags -> barrier ->
//   stage 8x8B coalesced agent loads -> ds_write_b64 (4-way banks) ->
//   barrier -> MFMA -> gates -> h tile to LDS -> transpose-read ->
//   16x8B agent stores/wave -> barrier (drains h) -> tid0 flag ->
//   out stores (off sync path).
// ---------------------------------------------------------------------------
__global__ __launch_bounds__(256, 1) void lstm_kernel(
    const _Float16* __restrict__ Whh,  // [4096][1024] quantized
    const float* __restrict__ bhh,     // [4096] quantized
    const _Float16* __restrict__ gx,   // packed [256][8][32][128][8]
    const float* __restrict__ c0,      // [64][1024]
    _Float16* __restrict__ hbuf,       // [8][2][8][1024] fp16
    float* __restrict__ out,           // [64][256][1024] ++ h_n ++ c_n
    unsigned* __restrict__ flags)      // [8][32]
{
  // Residency pin: force total regs/wave > 256 -> 1 wave/SIMD -> 1 block/CU.
  asm volatile("v_accvgpr_write_b32 a255, 0" ::: "a255");

  const int tid = threadIdx.x;
  const int lane = tid & 63;
  const int w = tid >> 6;
  const int cl = lane & 15, q = lane >> 4;
  const int g01 = (lane >> 3) & 1;
  const int c7 = lane & 7;

  const int grp = blockIdx.x & 7;    // batch octet
  const int rank = blockIdx.x >> 3;  // 32-column slice owner

  const int jbase = (rank << 5) + (w << 3);         // block/wave col base
  const int row0 = (g01 << 10) + jbase + c7;        // gates i/f
  const int row1 = ((g01 + 2) << 10) + jbase + c7;  // gates g/o

  // persistent B fragments: 2 tiles x 32 k-steps x 4 regs = 256 regs
  h8 B0[32], B1[32];
#pragma unroll
  for (int kt = 0; kt < 32; kt++) {
    B0[kt] = *(const h8*)(Whh + (size_t)row0 * 1024 + (kt << 5) + (q << 3));
    B1[kt] = *(const h8*)(Whh + (size_t)row1 * 1024 + (kt << 5) + (q << 3));
  }
  const float bh0 = bhh[row0], bh1 = bhh[row1];
  const int jc = jbase + c7;        // h column 0..1023
  const int lrow = ((q & 1) << 2);  // local batch row base (valid q<2)
  const bool writer = ((lane & 8) == 0) && (q < 2);

  float c_st[4], h_last[4];
#pragma unroll
  for (int r = 0; r < 4; r++) {
    c_st[r] = c0[((grp << 3) + lrow + r) * 1024 + jc];
    h_last[r] = 0.0f;
  }

  // LDS h stage: 8 rows x 1032 halves (pad +8: fragment reads arow*1032 are
  // conflict-free, verified in R6). Staging: thread (row=tid>>5, c=tid&31)
  // loads u64s c+32j of its row (coalesced 256B/32 lanes), writes LDS at
  // row*1032 + 4c + 128j halves -> 4-way banks. Tail 256 halves: per-wave
  // 64-half h-publication scratch tile (R13).
  __shared__ alignas(16) _Float16 hs[8 * 1032 + 4 * 64];
  const int arow = cl & 7;
  const u64* hb64 = (const u64*)hbuf;  // [grp: 4096][buf: 2048] u64s
  const size_t lsrc = (size_t)grp * 4096 + (size_t)((tid >> 5) << 8) + (tid & 31);
  _Float16* ldst = hs + (tid >> 5) * 1032 + ((tid & 31) << 2);
  _Float16* ts = hs + 8 * 1032 + w * 64;  // per-wave [8 rows][8 cols] tile

  unsigned* myflag = flags + (grp << 5) + rank;
  const u64* f2 = (const u64*)(flags + (grp << 5));  // 16 u64 per group

  for (int t = 0; t < 256; t++) {
    // prefetch gx_t: one coalesced 16B load per lane (overlaps the poll)
    const h8 gv8 = *(const h8*)(
        gx +
        ((((size_t)t * 8 + grp) * 32 + rank) * 128 + ((w << 5) | (lane & 31))) *
            8);

    if (t) {
      if (w == 0) {
        const unsigned tt = (unsigned)t;
        int it = 0;
        for (;;) {
          u64 v = __hip_atomic_load(&f2[lane & 15], __ATOMIC_RELAXED,
                                    __HIP_MEMORY_SCOPE_AGENT);
          bool ok = ((unsigned)v >= tt) && ((unsigned)(v >> 32) >= tt);
          if (__ballot(ok) == ~0ull) break;
          if (++it > (1 << 14)) break;  // hang insurance (loudly wrong)
          __builtin_amdgcn_s_sleep(1);
        }
      }
      __syncthreads();
    }

    // ---- stage h_t (16KB): 8 coalesced 8B agent loads -> ds_write_b64 ----
    {
      const u64* src = hb64 + lsrc + (size_t)(t & 1) * 2048;
      u64 v0 = __hip_atomic_load(src + 0 * 32, __ATOMIC_RELAXED, __HIP_MEMORY_SCOPE_AGENT);
      u64 v1 = __hip_atomic_load(src + 1 * 32, __ATOMIC_RELAXED, __HIP_MEMORY_SCOPE_AGENT);
      u64 v2 = __hip_atomic_load(src + 2 * 32, __ATOMIC_RELAXED, __HIP_MEMORY_SCOPE_AGENT);
      u64 v3 = __hip_atomic_load(src + 3 * 32, __ATOMIC_RELAXED, __HIP_MEMORY_SCOPE_AGENT);
      u64 v4 = __hip_atomic_load(src + 4 * 32, __ATOMIC_RELAXED, __HIP_MEMORY_SCOPE_AGENT);
      u64 v5 = __hip_atomic_load(src + 5 * 32, __ATOMIC_RELAXED, __HIP_MEMORY_SCOPE_AGENT);
      u64 v6 = __hip_atomic_load(src + 6 * 32, __ATOMIC_RELAXED, __HIP_MEMORY_SCOPE_AGENT);
      u64 v7 = __hip_atomic_load(src + 7 * 32, __ATOMIC_RELAXED, __HIP_MEMORY_SCOPE_AGENT);
      *(u64*)(ldst + 0 * 128) = v0;
      *(u64*)(ldst + 1 * 128) = v1;
      *(u64*)(ldst + 2 * 128) = v2;
      *(u64*)(ldst + 3 * 128) = v3;
      *(u64*)(ldst + 4 * 128) = v4;
      *(u64*)(ldst + 5 * 128) = v5;
      *(u64*)(ldst + 6 * 128) = v6;
      *(u64*)(ldst + 7 * 128) = v7;
    }
    __syncthreads();

    f4 a0 = {}, a1 = {}, a2 = {}, a3 = {};
#pragma unroll
    for (int kt = 0; kt < 32; kt++) {
      h8 av = *(const h8*)(hs + arow * 1032 + (kt << 5) + (q << 3));
      if (kt & 1) { a1 = MFMA16(av, B0[kt], a1); a3 = MFMA16(av, B1[kt], a3); }
      else        { a0 = MFMA16(av, B0[kt], a0); a2 = MFMA16(av, B1[kt], a2); }
    }
    f4 g0 = a0 + a1;
    f4 g1 = a2 + a3;

    _Float16* hbw = hbuf + (size_t)grp * 16384 + ((t + 1) & 1) * 8192;
#pragma unroll
    for (int r = 0; r < 4; r++) {
      float gv0 = fxp((float)gv8[r] + fxp(g0[r] + bh0));      // i or f
      float gv1 = fxp((float)gv8[4 + r] + fxp(g1[r] + bh1));  // g or o
      float s0 = fxp_rnd(hsig(gv0));                        // in [0,1]
      float s1t = fxp_rnd(fminf(fmaxf(gv1, -1.0f), 1.0f));  // in [-1,1]
      float s1s = fxp_rnd(hsig(gv1));
      float s1 = (lane & 8) ? s1s : s1t;
      float p0 = __shfl_xor(s0, 8);
      float p1 = __shfl_xor(s1, 8);
      float iv = writer ? s0 : p0;
      float fv = writer ? p0 : s0;
      float gv = writer ? s1 : p1;
      float ov = writer ? p1 : s1;
      float cn = fxp(fv * c_st[r] + iv * gv);
      c_st[r] = cn;
      float hn = fxp_rnd(ov * fminf(fmaxf(cn, -1.0f), 1.0f));  // in [-1,1]
      h_last[r] = hn;
      // R13: deposit h into the per-wave LDS tile instead of a scattered 2B
      // agent store. Writes (row = lrow+r, col = c7) at stride 8 -> 16 lanes
      // over 2x16B regions per r = 2 lanes/bank (free).
      if (writer) ts[(lrow + r) * 8 + c7] = (_Float16)hn;
    }
    // wave-local: ds ops of one wave complete in order; wait for the tile,
    // then lanes 0-15 transpose-read (b64, 16 distinct bank-pairs) and issue
    // 16 contiguous 8B agent stores (two lanes = 16B run per row).
    asm volatile("s_waitcnt lgkmcnt(0)" ::: "memory");
    if (lane < 16) {
      u64 hv = *(const u64*)(ts + (lane >> 1) * 8 + ((lane & 1) << 2));
      __hip_atomic_store(
          (u64*)&hbw[(lane >> 1) * 1024 + jbase + ((lane & 1) << 2)], hv,
          __ATOMIC_RELAXED, __HIP_MEMORY_SCOPE_AGENT);
    }
    __syncthreads();  // drains the h stores (out stores not yet issued)
    if (tid == 0)
      __hip_atomic_store(myflag, (unsigned)(t + 1), __ATOMIC_RELAXED,
                         __HIP_MEMORY_SCOPE_AGENT);
    // out stores after the flag: drain overlaps the next step's poll/stage
    if (writer) {
#pragma unroll
      for (int r = 0; r < 4; r++)
        __builtin_nontemporal_store(
            h_last[r],
            &out[((size_t)((grp << 3) + lrow + r) * 256 + t) * 1024 + jc]);
    }
  }

  if (writer) {
#pragma unroll
    for (int r = 0; r < 4; r++) {
      out[16777216 + (size_t)((grp << 3) + lrow + r) * 1024 + jc] = h_last[r];
      out[16777216 + 65536 + (size_t)((grp << 3) + lrow + r) * 1024 + jc] =
          c_st[r];
    }
  }
}

// ---------------------------------------------------------------------------
extern "C" void kernel_launch(void* const* d_in, const int* in_sizes, int n_in,
                              void* d_out, int out_size, void* d_ws,
                              size_t ws_size, hipStream_t stream) {
  const float* x    = (const float*)d_in[0];
  const float* w_ih = (const float*)d_in[1];
  const float* w_hh = (const float*)d_in[2];
  const float* b_ih = (const float*)d_in[3];
  const float* b_hh = (const float*)d_in[4];
  const float* h0   = (const float*)d_in[5];
  const float* c0   = (const float*)d_in[6];
  float* out = (float*)d_out;

  // workspace layout (bytes); total ~156.3 MB
  char* ws = (char*)d_ws;
  unsigned* flags = (unsigned*)ws;                    // [8][32] u32 = 1 KB
  _Float16* hbuf  = (_Float16*)(ws + 2048);           // 8*2*8*1024*2 = 256 KB
  _Float16* whhq  = (_Float16*)(ws + 264192);         // 8 MB
  _Float16* wihq  = (_Float16*)(ws + 8652800);        // 4 MB
  float*    bihq  = (float*)(ws + 12847104);          // 16 KB
  float*    bhhq  = (float*)(ws + 12863488);          // 16 KB
  _Float16* xq    = (_Float16*)(ws + 12879872);       // 16 MB
  _Float16* gxb   = (_Float16*)(ws + 29657088);       // 128 MB packed

  hipMemsetAsync(flags, 0, 2048, stream);
  qf16_kernel<<<dim3(4096), 256, 0, stream>>>(w_hh, whhq, 4194304 / 4);
  qf16_kernel<<<dim3(2048), 256, 0, stream>>>(w_ih, wihq, 2097152 / 4);
  qx_kernel<<<dim3(8192), 256, 0, stream>>>(x, xq);
  qh0_kernel<<<dim3(64), 256, 0, stream>>>(h0, hbuf);
  qf32_kernel<<<dim3(4), 256, 0, stream>>>(b_ih, bihq, 4096 / 4);
  qf32_kernel<<<dim3(4), 256, 0, stream>>>(b_hh, bhhq, 4096 / 4);
  gemm_gx_kernel<<<dim3(128, 32), 256, 0, stream>>>(xq, wihq, bihq, gxb);
  lstm_kernel<<<dim3(256), 256, 0, stream>>>(whhq, bhhq, gxb, c0, hbuf, out,
                                             flags);
}